// Round 1
// baseline (329.950 us; speedup 1.0000x reference)
//
#include <hip/hip_runtime.h>
#include <hip/hip_bf16.h>
#include <stdint.h>

// ---------------------------------------------------------------------------
// Fused edge-MLP + scatter GroupNorm block for MI355X (gfx950).
// Design:
//  - Node-level precompute: QC = relu(gn(agts@W_q))@W_c1[128:256] (bf16),
//    CC = ctx@W_c1[256:384] (bf16), A = agts@W_a (f32, written to d_out).
//  - Edge kernel: per 64-edge block, 3 chained bf16 MFMA GEMMs
//    (W_d2 -> gn -> W_c1[0:128] + QC[hi] + CC[wi] -> gn -> W_c2),
//    in-register GroupNorm, atomicAdd scatter into d_out.
//  - Final kernel: relu(gn(d_out)) @ W_l -> gn -> relu(+agts), in place.
//  - Weights pre-transposed (Wt[n][k]=W[k][n]) + XOR-swizzled into ws so LDS
//    staging is a linear copy and ds_read_b128 B-fragment reads are
//    conflict-free. MFMA 16x16x32 bf16; C layout col=lane&15,
//    row=(lane>>4)*4+reg (HW-verified). A/B use identical k-mapping so any
//    k-permutation mismatch vs HW cancels.
// ---------------------------------------------------------------------------

typedef __bf16 bf16_t;
typedef __bf16 bfx8 __attribute__((ext_vector_type(8)));
typedef float f32x4 __attribute__((ext_vector_type(4)));

__device__ __forceinline__ unsigned short f2bfu(float f) {
  unsigned u = __builtin_bit_cast(unsigned, f);
  return (unsigned short)((u + 0x7fffu + ((u >> 16) & 1u)) >> 16);
}
__device__ __forceinline__ float bfu2f(unsigned short u) {
  return __builtin_bit_cast(float, ((unsigned)u) << 16);
}
__device__ __forceinline__ unsigned pk2(unsigned x, unsigned y) {
  float lo = bfu2f((unsigned short)(x & 0xffffu)) + bfu2f((unsigned short)(y & 0xffffu));
  float hi = bfu2f((unsigned short)(x >> 16)) + bfu2f((unsigned short)(y >> 16));
  return (unsigned)f2bfu(lo) | ((unsigned)f2bfu(hi) << 16);
}

// swizzled byte offset of element (row, k) in a [rows][128] bf16 LDS tile
__device__ __forceinline__ int swzb(int row, int kbyte) {
  return (row * 256 + kbyte) ^ ((row & 7) << 4);
}

// linear copy of one pre-swizzled transposed weight (32768 B) into LDS
__device__ __forceinline__ void stage_weight(const unsigned short* wsrc, char* WtL, int tid) {
  const uint4* s = (const uint4*)wsrc;
  uint4* d = (uint4*)WtL;
#pragma unroll
  for (int i = 0; i < 8; ++i) d[tid + i * 256] = s[tid + i * 256];
}

// wave GEMM: [16 rows x 128] @ [128 x 128] -> acc[8] tiles (16x16 each)
template <bool A_FROM_LDS>
__device__ __forceinline__ void wave_gemm(const char* WtL, const char* XL,
                                          const bfx8* aF, f32x4 acc[8],
                                          int lg, int lr) {
#pragma unroll
  for (int ks = 0; ks < 4; ++ks) {
    bfx8 a;
    if (A_FROM_LDS)
      a = *(const bfx8*)(XL + swzb(lr, (ks * 32 + lg * 8) * 2));
    else
      a = aF[ks];
#pragma unroll
    for (int t = 0; t < 8; ++t) {
      int n = t * 16 + lr;
      bfx8 b = *(const bfx8*)(WtL + swzb(n, (ks * 32 + lg * 8) * 2));
      acc[t] = __builtin_amdgcn_mfma_f32_16x16x32_bf16(a, b, acc[t], 0, 0, 0);
    }
  }
}

// in-register GroupNorm(1 group over 128 ch) on C-layout accumulators
__device__ __forceinline__ void wave_gn(f32x4 acc[8], const float* g, const float* b,
                                        int lg, int lr, bool do_relu) {
  float s0 = 0.f, s1 = 0.f, s2 = 0.f, s3 = 0.f;
  float q0 = 0.f, q1 = 0.f, q2 = 0.f, q3 = 0.f;
#pragma unroll
  for (int t = 0; t < 8; ++t) {
    float v0 = acc[t][0], v1 = acc[t][1], v2 = acc[t][2], v3 = acc[t][3];
    s0 += v0; q0 += v0 * v0;
    s1 += v1; q1 += v1 * v1;
    s2 += v2; q2 += v2 * v2;
    s3 += v3; q3 += v3 * v3;
  }
#pragma unroll
  for (int m = 1; m <= 8; m <<= 1) {
    s0 += __shfl_xor(s0, m, 64); q0 += __shfl_xor(q0, m, 64);
    s1 += __shfl_xor(s1, m, 64); q1 += __shfl_xor(q1, m, 64);
    s2 += __shfl_xor(s2, m, 64); q2 += __shfl_xor(q2, m, 64);
    s3 += __shfl_xor(s3, m, 64); q3 += __shfl_xor(q3, m, 64);
  }
  float gc[8], bc[8];
#pragma unroll
  for (int t = 0; t < 8; ++t) { gc[t] = g[t * 16 + lr]; bc[t] = b[t * 16 + lr]; }
  float mean[4], rstd[4];
  {
    const float inv = 1.f / 128.f;
    float m0 = s0 * inv, m1 = s1 * inv, m2 = s2 * inv, m3 = s3 * inv;
    mean[0] = m0; mean[1] = m1; mean[2] = m2; mean[3] = m3;
    rstd[0] = rsqrtf(q0 * inv - m0 * m0 + 1e-5f);
    rstd[1] = rsqrtf(q1 * inv - m1 * m1 + 1e-5f);
    rstd[2] = rsqrtf(q2 * inv - m2 * m2 + 1e-5f);
    rstd[3] = rsqrtf(q3 * inv - m3 * m3 + 1e-5f);
  }
#pragma unroll
  for (int t = 0; t < 8; ++t) {
#pragma unroll
    for (int r = 0; r < 4; ++r) {
      float v = (acc[t][r] - mean[r]) * rstd[r] * gc[t] + bc[t];
      if (do_relu) v = fmaxf(v, 0.f);
      acc[t][r] = v;
    }
  }
}

// write post-GN tile (C-layout) into wave-private swizzled LDS stage as bf16
__device__ __forceinline__ void wave_stage(char* XL, const f32x4 acc[8], int lg, int lr) {
#pragma unroll
  for (int t = 0; t < 8; ++t) {
#pragma unroll
    for (int r = 0; r < 4; ++r) {
      int row = 4 * lg + r, c = t * 16 + lr;
      *(unsigned short*)(XL + swzb(row, 2 * c)) = f2bfu(acc[t][r]);
    }
  }
}

// ---------------------------------------------------------------------------
// prep: transpose + bf16-convert + pre-swizzle the 8 [128x128] weights into ws
// order: 0 W_d2, 1 W_c1_top, 2 W_c1_mid, 3 W_c1_bot, 4 W_c2, 5 W_q, 6 W_a, 7 W_l
// ---------------------------------------------------------------------------
__global__ void k_prep_weights(const float* Wd2, const float* Wc1, const float* Wc2,
                               const float* Wq, const float* Wa, const float* Wl,
                               unsigned short* wsW) {
  __shared__ unsigned short tmp[128 * 128];
  int m = blockIdx.x;
  const float* src;
  switch (m) {
    case 0: src = Wd2; break;
    case 1: src = Wc1; break;
    case 2: src = Wc1 + 128 * 128; break;
    case 3: src = Wc1 + 256 * 128; break;
    case 4: src = Wc2; break;
    case 5: src = Wq; break;
    case 6: src = Wa; break;
    default: src = Wl; break;
  }
  int tid = threadIdx.x;
#pragma unroll
  for (int i = 0; i < 16; ++i) {
    int lin = i * 256 + tid;  // quad index: k*32 + q
    float4 v = ((const float4*)src)[lin];
    ushort4 b;
    b.x = f2bfu(v.x); b.y = f2bfu(v.y); b.z = f2bfu(v.z); b.w = f2bfu(v.w);
    *(ushort4*)&tmp[lin * 4] = b;
  }
  __syncthreads();
  unsigned short* dst = wsW + (size_t)m * 16384;
#pragma unroll
  for (int i = 0; i < 16; ++i) {
    int lin = i * 256 + tid;
    int n = lin >> 5, q = lin & 31, k0 = q * 4;
    ushort4 b;
    b.x = tmp[(k0 + 0) * 128 + n];
    b.y = tmp[(k0 + 1) * 128 + n];
    b.z = tmp[(k0 + 2) * 128 + n];
    b.w = tmp[(k0 + 3) * 128 + n];
    *(ushort4*)((char*)dst + swzb(n, k0 * 2)) = b;
  }
}

// ---------------------------------------------------------------------------
// ctx precompute: CC = ctx @ W_c1_bot  (bf16 out)
// ---------------------------------------------------------------------------
__global__ __launch_bounds__(256, 2) void k_ctx(const float* ctx, const unsigned short* wsW,
                                                unsigned short* cc, int M) {
  __shared__ __align__(16) char lds[32768];
  int tid = threadIdx.x, wid = tid >> 6, lane = tid & 63, lg = lane >> 4, lr = lane & 15;
  int base = blockIdx.x * 64;
  stage_weight(wsW + 3 * 16384, lds, tid);
  int row = base + 16 * wid + lr;
  int rload = row < M ? row : M - 1;
  bfx8 cf[4];
#pragma unroll
  for (int ks = 0; ks < 4; ++ks) {
    int k0 = ks * 32 + lg * 8;
    const float4* p = (const float4*)&ctx[(size_t)rload * 128 + k0];
    float4 a = p[0], b = p[1];
    bfx8 f;
    f[0] = (__bf16)a.x; f[1] = (__bf16)a.y; f[2] = (__bf16)a.z; f[3] = (__bf16)a.w;
    f[4] = (__bf16)b.x; f[5] = (__bf16)b.y; f[6] = (__bf16)b.z; f[7] = (__bf16)b.w;
    cf[ks] = f;
  }
  __syncthreads();
  f32x4 acc[8];
#pragma unroll
  for (int t = 0; t < 8; ++t) acc[t] = 0.f;
  wave_gemm<false>(lds, nullptr, cf, acc, lg, lr);
#pragma unroll
  for (int r = 0; r < 4; ++r) {
    int grow = base + 16 * wid + 4 * lg + r;
    if (grow < M) {
#pragma unroll
      for (int t = 0; t < 8; ++t)
        cc[(size_t)grow * 128 + t * 16 + lr] = f2bfu(acc[t][r]);
    }
  }
}

// ---------------------------------------------------------------------------
// agent precompute: QC = relu(gn(agts@W_q))@W_c1_mid (bf16); A = agts@W_a (f32->d_out)
// ---------------------------------------------------------------------------
__global__ __launch_bounds__(256, 2) void k_agents(const float* agts, const float* g_q,
                                                   const float* b_q, const unsigned short* wsW,
                                                   unsigned short* qc, float* outA, int N) {
  __shared__ __align__(16) char lds[49152];
  char* WtL = lds;
  char* XL = lds + 32768;
  int tid = threadIdx.x, wid = tid >> 6, lane = tid & 63, lg = lane >> 4, lr = lane & 15;
  int base = blockIdx.x * 64;
  stage_weight(wsW + 5 * 16384, WtL, tid);  // W_q
  int row = base + 16 * wid + lr;
  int rload = row < N ? row : N - 1;
  bfx8 agf[4];
#pragma unroll
  for (int ks = 0; ks < 4; ++ks) {
    int k0 = ks * 32 + lg * 8;
    const float4* p = (const float4*)&agts[(size_t)rload * 128 + k0];
    float4 a = p[0], b = p[1];
    bfx8 f;
    f[0] = (__bf16)a.x; f[1] = (__bf16)a.y; f[2] = (__bf16)a.z; f[3] = (__bf16)a.w;
    f[4] = (__bf16)b.x; f[5] = (__bf16)b.y; f[6] = (__bf16)b.z; f[7] = (__bf16)b.w;
    agf[ks] = f;
  }
  __syncthreads();
  f32x4 acc[8];
#pragma unroll
  for (int t = 0; t < 8; ++t) acc[t] = 0.f;
  wave_gemm<false>(WtL, nullptr, agf, acc, lg, lr);
  wave_gn(acc, g_q, b_q, lg, lr, true);
  wave_stage(XL + wid * 4096, acc, lg, lr);
  __syncthreads();
  stage_weight(wsW + 2 * 16384, WtL, tid);  // W_c1_mid
  __syncthreads();
#pragma unroll
  for (int t = 0; t < 8; ++t) acc[t] = 0.f;
  wave_gemm<true>(WtL, XL + wid * 4096, nullptr, acc, lg, lr);
#pragma unroll
  for (int r = 0; r < 4; ++r) {
    int grow = base + 16 * wid + 4 * lg + r;
    if (grow < N) {
#pragma unroll
      for (int t = 0; t < 8; ++t)
        qc[(size_t)grow * 128 + t * 16 + lr] = f2bfu(acc[t][r]);
    }
  }
  __syncthreads();
  stage_weight(wsW + 6 * 16384, WtL, tid);  // W_a
  __syncthreads();
#pragma unroll
  for (int t = 0; t < 8; ++t) acc[t] = 0.f;
  wave_gemm<false>(WtL, nullptr, agf, acc, lg, lr);
#pragma unroll
  for (int r = 0; r < 4; ++r) {
    int grow = base + 16 * wid + 4 * lg + r;
    if (grow < N) {
#pragma unroll
      for (int t = 0; t < 8; ++t)
        outA[(size_t)grow * 128 + t * 16 + lr] = acc[t][r];
    }
  }
}

// ---------------------------------------------------------------------------
// edge kernel: 64 edges/block; d1 -> W_d2/gn -> +QC+CC, W_c1_top/gn -> W_c2
// -> atomicAdd into out[hi].
// ---------------------------------------------------------------------------
__global__ __launch_bounds__(256, 2) void k_edge(
    const float* agt_ctrs, const float* ctx_ctrs, const int* hi, const int* wi,
    const float* W_d1, const float* b_d1, const float* g_d2, const float* b_d2,
    const float* g_c1, const float* b_c1, const unsigned short* wsW,
    const unsigned short* qc, const unsigned short* cc, float* out, int E) {
  __shared__ __align__(16) char lds[65536];
  char* WtL = lds;           // 32768: weight tile
  char* XL = lds + 32768;    // 16384: 4 waves x 4096 activation stage
  char* QCCL = lds + 49152;  // 16384: 64 rows x 256B gathered QC+CC (bf16)
  int tid = threadIdx.x, wid = tid >> 6, lane = tid & 63, lg = lane >> 4, lr = lane & 15;
  int blockBase = blockIdx.x * 64;

  stage_weight(wsW + 0 * 16384, WtL, tid);  // W_d2

  // gather QC[hi]+CC[wi] for the block's 64 edges into LDS (bf16 sum)
  {
    int r = tid >> 2, qq = tid & 3;
    int e = blockBase + r;
    if (e >= E) e = E - 1;
    int h2 = hi[e], w2 = wi[e];
    const uint4* qrow = (const uint4*)(qc + (size_t)h2 * 128);
    const uint4* crow = (const uint4*)(cc + (size_t)w2 * 128);
#pragma unroll
    for (int i = 0; i < 4; ++i) {
      uint4 av = qrow[qq * 4 + i];
      uint4 bv = crow[qq * 4 + i];
      uint4 o;
      o.x = pk2(av.x, bv.x);
      o.y = pk2(av.y, bv.y);
      o.z = pk2(av.z, bv.z);
      o.w = pk2(av.w, bv.w);
      int c0 = qq * 32 + i * 8;
      *(uint4*)(QCCL + swzb(r, 2 * c0)) = o;
    }
  }

  // d1 = relu(dist @ W_d1 + b_d1) directly in A-fragment layout
  bfx8 d1f[4];
  {
    int e = blockBase + 16 * wid + lr;
    if (e >= E) e = E - 1;
    int h2 = hi[e], w2 = wi[e];
    float dx = agt_ctrs[2 * h2] - ctx_ctrs[2 * w2];
    float dy = agt_ctrs[2 * h2 + 1] - ctx_ctrs[2 * w2 + 1];
#pragma unroll
    for (int ks = 0; ks < 4; ++ks) {
      int k0 = ks * 32 + lg * 8;
      const float4* w0 = (const float4*)&W_d1[k0];
      const float4* w1 = (const float4*)&W_d1[128 + k0];
      const float4* bp = (const float4*)&b_d1[k0];
      float4 w0a = w0[0], w0b = w0[1];
      float4 w1a = w1[0], w1b = w1[1];
      float4 ba = bp[0], bb = bp[1];
      bfx8 f;
      f[0] = (__bf16)fmaxf(dx * w0a.x + dy * w1a.x + ba.x, 0.f);
      f[1] = (__bf16)fmaxf(dx * w0a.y + dy * w1a.y + ba.y, 0.f);
      f[2] = (__bf16)fmaxf(dx * w0a.z + dy * w1a.z + ba.z, 0.f);
      f[3] = (__bf16)fmaxf(dx * w0a.w + dy * w1a.w + ba.w, 0.f);
      f[4] = (__bf16)fmaxf(dx * w0b.x + dy * w1b.x + bb.x, 0.f);
      f[5] = (__bf16)fmaxf(dx * w0b.y + dy * w1b.y + bb.y, 0.f);
      f[6] = (__bf16)fmaxf(dx * w0b.z + dy * w1b.z + bb.z, 0.f);
      f[7] = (__bf16)fmaxf(dx * w0b.w + dy * w1b.w + bb.w, 0.f);
      d1f[ks] = f;
    }
  }
  __syncthreads();

  f32x4 acc[8];
#pragma unroll
  for (int t = 0; t < 8; ++t) acc[t] = 0.f;
  wave_gemm<false>(WtL, nullptr, d1f, acc, lg, lr);  // d1 @ W_d2
  wave_gn(acc, g_d2, b_d2, lg, lr, true);
  wave_stage(XL + wid * 4096, acc, lg, lr);
  __syncthreads();
  stage_weight(wsW + 1 * 16384, WtL, tid);  // W_c1_top
  __syncthreads();

  // acc init = QC[hi] + CC[wi]; then += d2 @ W_c1_top
#pragma unroll
  for (int t = 0; t < 8; ++t) {
#pragma unroll
    for (int r = 0; r < 4; ++r) {
      int row = 16 * wid + 4 * lg + r, c = t * 16 + lr;
      acc[t][r] = bfu2f(*(const unsigned short*)(QCCL + swzb(row, 2 * c)));
    }
  }
  wave_gemm<true>(WtL, XL + wid * 4096, nullptr, acc, lg, lr);
  wave_gn(acc, g_c1, b_c1, lg, lr, true);
  wave_stage(XL + wid * 4096, acc, lg, lr);
  __syncthreads();
  stage_weight(wsW + 4 * 16384, WtL, tid);  // W_c2
  __syncthreads();

#pragma unroll
  for (int t = 0; t < 8; ++t) acc[t] = 0.f;
  wave_gemm<true>(WtL, XL + wid * 4096, nullptr, acc, lg, lr);  // msg = h @ W_c2

  // scatter-add msg into out[hi]
#pragma unroll
  for (int r = 0; r < 4; ++r) {
    int erow = blockBase + 16 * wid + 4 * lg + r;
    if (erow < E) {
      int hh = hi[erow];
      float* dst = out + (size_t)hh * 128 + lr;
#pragma unroll
      for (int t = 0; t < 8; ++t) atomicAdd(dst + t * 16, acc[t][r]);
    }
  }
}

// ---------------------------------------------------------------------------
// final: a = relu(gn(A,g_n,b_n)); a = gn(a@W_l,g_l,b_l); out = relu(a+agts)
// in place on d_out.
// ---------------------------------------------------------------------------
__global__ __launch_bounds__(256, 2) void k_final(const float* agts, const float* g_n,
                                                  const float* b_n, const float* g_l,
                                                  const float* b_l, const unsigned short* wsW,
                                                  float* io, int N) {
  __shared__ __align__(16) char lds[32768];
  int tid = threadIdx.x, wid = tid >> 6, lane = tid & 63, lg = lane >> 4, lr = lane & 15;
  int base = blockIdx.x * 64;
  stage_weight(wsW + 7 * 16384, lds, tid);  // W_l
  int row = base + 16 * wid + lr;
  int rload = row < N ? row : N - 1;

  float xv[4][8];
  float s = 0.f, q = 0.f;
#pragma unroll
  for (int ks = 0; ks < 4; ++ks) {
    int k0 = ks * 32 + lg * 8;
    const float4* p = (const float4*)&io[(size_t)rload * 128 + k0];
    float4 a = p[0], b = p[1];
    xv[ks][0] = a.x; xv[ks][1] = a.y; xv[ks][2] = a.z; xv[ks][3] = a.w;
    xv[ks][4] = b.x; xv[ks][5] = b.y; xv[ks][6] = b.z; xv[ks][7] = b.w;
    s += a.x + a.y + a.z + a.w + b.x + b.y + b.z + b.w;
    q += a.x * a.x + a.y * a.y + a.z * a.z + a.w * a.w +
         b.x * b.x + b.y * b.y + b.z * b.z + b.w * b.w;
  }
  s += __shfl_xor(s, 16, 64); q += __shfl_xor(q, 16, 64);
  s += __shfl_xor(s, 32, 64); q += __shfl_xor(q, 32, 64);
  float mean = s * (1.f / 128.f);
  float var = q * (1.f / 128.f) - mean * mean;
  float rstd = rsqrtf(var + 1e-5f);

  bfx8 xf[4];
#pragma unroll
  for (int ks = 0; ks < 4; ++ks) {
    int k0 = ks * 32 + lg * 8;
    const float4* gp = (const float4*)&g_n[k0];
    const float4* bp = (const float4*)&b_n[k0];
    float4 g0 = gp[0], g1 = gp[1];
    float4 b0 = bp[0], b1 = bp[1];
    bfx8 f;
    f[0] = (__bf16)fmaxf((xv[ks][0] - mean) * rstd * g0.x + b0.x, 0.f);
    f[1] = (__bf16)fmaxf((xv[ks][1] - mean) * rstd * g0.y + b0.y, 0.f);
    f[2] = (__bf16)fmaxf((xv[ks][2] - mean) * rstd * g0.z + b0.z, 0.f);
    f[3] = (__bf16)fmaxf((xv[ks][3] - mean) * rstd * g0.w + b0.w, 0.f);
    f[4] = (__bf16)fmaxf((xv[ks][4] - mean) * rstd * g1.x + b1.x, 0.f);
    f[5] = (__bf16)fmaxf((xv[ks][5] - mean) * rstd * g1.y + b1.y, 0.f);
    f[6] = (__bf16)fmaxf((xv[ks][6] - mean) * rstd * g1.z + b1.z, 0.f);
    f[7] = (__bf16)fmaxf((xv[ks][7] - mean) * rstd * g1.w + b1.w, 0.f);
    xf[ks] = f;
  }
  __syncthreads();

  f32x4 acc[8];
#pragma unroll
  for (int t = 0; t < 8; ++t) acc[t] = 0.f;
  wave_gemm<false>(lds, nullptr, xf, acc, lg, lr);
  wave_gn(acc, g_l, b_l, lg, lr, false);

#pragma unroll
  for (int r = 0; r < 4; ++r) {
    int grow = base + 16 * wid + 4 * lg + r;
    if (grow < N) {
#pragma unroll
      for (int t = 0; t < 8; ++t) {
        int c = t * 16 + lr;
        float res = agts[(size_t)grow * 128 + c];
        io[(size_t)grow * 128 + c] = fmaxf(acc[t][r] + res, 0.f);
      }
    }
  }
}

// ---------------------------------------------------------------------------
extern "C" void kernel_launch(void* const* d_in, const int* in_sizes, int n_in,
                              void* d_out, int out_size, void* d_ws, size_t ws_size,
                              hipStream_t stream) {
  const float* agts = (const float*)d_in[0];
  const float* ctx = (const float*)d_in[1];
  const float* agt_ctrs = (const float*)d_in[2];
  const float* ctx_ctrs = (const float*)d_in[3];
  const int* hi = (const int*)d_in[4];
  const int* wi = (const int*)d_in[5];
  const float* W_d1 = (const float*)d_in[6];
  const float* b_d1 = (const float*)d_in[7];
  const float* W_d2 = (const float*)d_in[8];
  const float* g_d2 = (const float*)d_in[9];
  const float* b_d2 = (const float*)d_in[10];
  const float* W_q = (const float*)d_in[11];
  const float* g_q = (const float*)d_in[12];
  const float* b_q = (const float*)d_in[13];
  const float* W_c1 = (const float*)d_in[14];
  const float* g_c1 = (const float*)d_in[15];
  const float* b_c1 = (const float*)d_in[16];
  const float* W_c2 = (const float*)d_in[17];
  const float* W_a = (const float*)d_in[18];
  const float* g_n = (const float*)d_in[19];
  const float* b_n = (const float*)d_in[20];
  const float* W_l = (const float*)d_in[21];
  const float* g_l = (const float*)d_in[22];
  const float* b_l = (const float*)d_in[23];

  int N = in_sizes[0] / 128;
  int M = in_sizes[1] / 128;
  int E = in_sizes[4];

  float* out = (float*)d_out;
  char* ws = (char*)d_ws;
  unsigned short* qc = (unsigned short*)ws;
  unsigned short* cc = (unsigned short*)(ws + (size_t)N * 128 * 2);
  unsigned short* wsW = (unsigned short*)(ws + (size_t)N * 128 * 2 + (size_t)M * 128 * 2);

  k_prep_weights<<<8, 256, 0, stream>>>(W_d2, W_c1, W_c2, W_q, W_a, W_l, wsW);
  k_ctx<<<(M + 63) / 64, 256, 0, stream>>>(ctx, wsW, cc, M);
  k_agents<<<(N + 63) / 64, 256, 0, stream>>>(agts, g_q, b_q, wsW, qc, out, N);
  k_edge<<<(E + 63) / 64, 256, 0, stream>>>(agt_ctrs, ctx_ctrs, hi, wi, W_d1, b_d1,
                                            g_d2, b_d2, g_c1, b_c1, wsW, qc, cc, out, E);
  k_final<<<(N + 63) / 64, 256, 0, stream>>>(agts, g_n, b_n, g_l, b_l, wsW, out, N);
}